// Round 2
// baseline (708.199 us; speedup 1.0000x reference)
//
#include <hip/hip_runtime.h>

// WindowAttention3D: x(256,343,384) -> qkv -> per-(b,h) softmax attention (+rel bias) -> proj
// bf16 MFMA everywhere, fp32 accum. Attention restructured: S^T = K*Q^T so P exits
// QK in the exact A-fragment layout of mfma_16x16x16_bf16 for PV (no LDS transpose).

#define M_TOT 87808   // 256*343
#define NTOK  343
#define NPAD  352
#define DIMC  384
#define NHEAD 12
#define QKVN  1152
#define BWIN  256

typedef __bf16 bf16x8 __attribute__((ext_vector_type(8)));
typedef __bf16 bf16x4 __attribute__((ext_vector_type(4)));
typedef float f32x4 __attribute__((ext_vector_type(4)));
typedef unsigned short u16x4 __attribute__((ext_vector_type(4)));

__device__ __forceinline__ unsigned short bf16rne(float f) {
  unsigned int u = __float_as_uint(f);
  u += 0x7fffu + ((u >> 16) & 1u);
  return (unsigned short)(u >> 16);
}

__device__ __forceinline__ unsigned int packbf(float lo, float hi) {
  return (unsigned int)bf16rne(lo) | ((unsigned int)bf16rne(hi) << 16);
}

// round-half-up bf16 pack of 4 floats -> A/B fragment for 16x16x16 bf16 MFMA
__device__ __forceinline__ bf16x4 pack_bf16x4(float a, float b, float c, float d) {
  unsigned ua = __float_as_uint(a) + 0x8000u;
  unsigned ub = __float_as_uint(b) + 0x8000u;
  unsigned uc = __float_as_uint(c) + 0x8000u;
  unsigned ud = __float_as_uint(d) + 0x8000u;
  unsigned lo = __builtin_amdgcn_perm(ub, ua, 0x07060302u);  // {a.hi16, b.hi16}
  unsigned hi = __builtin_amdgcn_perm(ud, uc, 0x07060302u);
  union { unsigned u[2]; bf16x4 v; } x;
  x.u[0] = lo; x.u[1] = hi;
  return x.v;
}

// ---------------- prep kernels ----------------

__global__ void cvt_x_kernel(const float* __restrict__ x, unsigned short* __restrict__ xb, int n8) {
  int i = blockIdx.x * 256 + threadIdx.x;
  if (i >= n8) return;
  const float4* xv = (const float4*)x + (size_t)i * 2;
  float4 a = xv[0], b = xv[1];
  uint4 o;
  o.x = packbf(a.x, a.y); o.y = packbf(a.z, a.w);
  o.z = packbf(b.x, b.y); o.w = packbf(b.z, b.w);
  ((uint4*)xb)[i] = o;
}

__global__ void prep_w_kernel(const float* __restrict__ qkv_w, const float* __restrict__ proj_w,
                              unsigned short* __restrict__ wqkvT, unsigned short* __restrict__ wprojT) {
  int tid = blockIdx.x * 256 + threadIdx.x;
  if (tid < QKVN * DIMC) {
    int n = tid / DIMC, k = tid - n * DIMC;
    wqkvT[tid] = bf16rne(qkv_w[(size_t)k * QKVN + n]);
  }
  if (tid < DIMC * DIMC) {
    int n = tid / DIMC, k = tid - n * DIMC;
    wprojT[tid] = bf16rne(proj_w[(size_t)k * DIMC + n]);
  }
}

// biasb[h][i][j] = bf16(bias_table[rel_idx[i][j]][h] * log2(e)); padded j -> 0
__global__ void prep_bias_kernel(const float* __restrict__ bias_table, const int* __restrict__ rel_idx,
                                 unsigned short* __restrict__ biasb) {
  int tid = blockIdx.x * 256 + threadIdx.x;
  if (tid >= NTOK * NPAD) return;
  int i = tid / NPAD, j = tid - i * NPAD;
  const float LOG2E = 1.44269504088896340f;
  if (j < NTOK) {
    int idx = rel_idx[i * NTOK + j];
    #pragma unroll
    for (int h = 0; h < NHEAD; h++)
      biasb[(size_t)h * (NTOK * NPAD) + tid] = bf16rne(bias_table[idx * NHEAD + h] * LOG2E);
  } else {
    #pragma unroll
    for (int h = 0; h < NHEAD; h++)
      biasb[(size_t)h * (NTOK * NPAD) + tid] = 0;
  }
}

// ---------------- GEMM (A[M][K] bf16, Bt[N][K] bf16, +bias) ----------------

typedef const __attribute__((address_space(1))) unsigned int* gas_t;
typedef __attribute__((address_space(3))) unsigned int* las_t;

__device__ __forceinline__ void load16_lds(const void* g, void* l) {
  __builtin_amdgcn_global_load_lds((gas_t)g, (las_t)l, 16, 0, 0);
}

template<bool OUT_BF16>
__global__ __launch_bounds__(256, 3) void gemm_bt_kernel(
    const unsigned short* __restrict__ A, const unsigned short* __restrict__ Bt,
    const float* __restrict__ bias, void* __restrict__ outp,
    int M, int Nn, int K)
{
  __shared__ __attribute__((aligned(16))) unsigned short Atile[128 * 64];
  __shared__ __attribute__((aligned(16))) unsigned short Btile[128 * 64];
  const int t = threadIdx.x;
  const int lane = t & 63, w = t >> 6;
  const int q = lane >> 4, l15 = lane & 15;
  const int m0 = blockIdx.y * 128, n0 = blockIdx.x * 128;
  const int wm = w >> 1, wn = w & 1;

  f32x4 acc[4][4] = {};

  for (int kk = 0; kk < K; kk += 64) {
    #pragma unroll
    for (int i = 0; i < 4; i++) {
      int chunk = i * 256 + t;
      int r = chunk >> 3, cl = chunk & 7;
      int cg = cl ^ (r & 7);
      load16_lds(A + (size_t)(m0 + r) * K + kk + cg * 8, Atile + chunk * 8);
      load16_lds(Bt + (size_t)(n0 + r) * K + kk + cg * 8, Btile + chunk * 8);
    }
    __syncthreads();
    const bf16x8* As = (const bf16x8*)Atile;
    const bf16x8* Bs = (const bf16x8*)Btile;
    #pragma unroll
    for (int kq = 0; kq < 2; kq++) {
      bf16x8 af[4], bfr[4];
      #pragma unroll
      for (int mt = 0; mt < 4; mt++) {
        int m = wm * 64 + mt * 16 + l15;
        af[mt] = As[m * 8 + ((kq * 4 + q) ^ (m & 7))];
      }
      #pragma unroll
      for (int nt = 0; nt < 4; nt++) {
        int nr = wn * 64 + nt * 16 + l15;
        bfr[nt] = Bs[nr * 8 + ((kq * 4 + q) ^ (nr & 7))];
      }
      #pragma unroll
      for (int mt = 0; mt < 4; mt++)
        #pragma unroll
        for (int nt = 0; nt < 4; nt++)
          acc[mt][nt] = __builtin_amdgcn_mfma_f32_16x16x32_bf16(af[mt], bfr[nt], acc[mt][nt], 0, 0, 0);
    }
    __syncthreads();
  }

  #pragma unroll
  for (int nt = 0; nt < 4; nt++) {
    int n = n0 + wn * 64 + nt * 16 + l15;
    float bv = bias[n];
    #pragma unroll
    for (int mt = 0; mt < 4; mt++) {
      int mb = m0 + wm * 64 + mt * 16 + q * 4;
      #pragma unroll
      for (int r = 0; r < 4; r++) {
        float v = acc[mt][nt][r] + bv;
        size_t off = (size_t)(mb + r) * Nn + n;
        if (OUT_BF16) ((unsigned short*)outp)[off] = bf16rne(v);
        else          ((float*)outp)[off] = v;
      }
    }
  }
}

// ---------------- attention: one block per (b,h); grid ordered h-major ----------------

#define VST 360  // V^T LDS row stride (elements)

__global__ __launch_bounds__(256, 6) void attn_kernel(
    const unsigned short* __restrict__ qkvb,   // [M_TOT][1152] bf16
    const unsigned short* __restrict__ biasb,  // [12][343][352] bf16 (pre * log2e)
    unsigned short* __restrict__ attnout)      // [M_TOT][384] bf16
{
  __shared__ __attribute__((aligned(16))) unsigned short Vt[32 * VST];  // V^T[d][j]
  const int bx = blockIdx.x;
  const int h = bx >> 8, b = bx & 255;        // h-major: bias slab stays L2-hot
  const int t = threadIdx.x;
  const int lane = t & 63, w = t >> 6;
  const int q = lane >> 4, l15 = lane & 15;

  const size_t base = (size_t)b * NTOK * QKVN;
  const unsigned short* Qg = qkvb + base + h * 32;
  const unsigned short* Kg = qkvb + base + DIMC + h * 32;
  const unsigned short* Vg = qkvb + base + 2 * DIMC + h * 32;

  // stage V^T; zero-pad j in [343,352) (avoid NaN garbage hitting MFMA)
  for (int chunk = t; chunk < NPAD * 4; chunk += 256) {
    int j = chunk >> 2, c = chunk & 3;
    uint4 vd = {0, 0, 0, 0};
    if (j < NTOK) vd = *(const uint4*)(Vg + (size_t)j * QKVN + c * 8);
    const unsigned short* vs = (const unsigned short*)&vd;
    #pragma unroll
    for (int u = 0; u < 8; u++)
      Vt[(c * 8 + u) * VST + j] = vs[u];
  }
  __syncthreads();

  const unsigned short* bh_bias = biasb + (size_t)h * (NTOK * NPAD);
  const float CS = 0.17677669529663689f * 1.44269504088896340f;  // scale * log2e

  for (int it = w; it < 22; it += 4) {
    int i0 = it * 16;
    int iq = i0 + l15; iq = iq > (NTOK - 1) ? (NTOK - 1) : iq;
    // Q as B-fragment: B[n=i][k=d], lane n=l15, k=q*8+u
    bf16x8 bq = *(const bf16x8*)(Qg + (size_t)iq * QKVN + q * 8);
    const unsigned short* brow = bh_bias + (size_t)iq * NPAD;

    f32x4 o0 = {0.f, 0.f, 0.f, 0.f}, o1 = {0.f, 0.f, 0.f, 0.f};
    float den = 0.f;

    #pragma unroll 2
    for (int jt = 0; jt < 22; jt++) {
      int j0 = jt * 16;
      int jr = j0 + l15; jr = jr > (NTOK - 1) ? (NTOK - 1) : jr;
      // K as A-fragment: A[m=j][k=d]
      bf16x8 ak = *(const bf16x8*)(Kg + (size_t)jr * QKVN + q * 8);
      f32x4 zero = {0.f, 0.f, 0.f, 0.f};
      // S^T tile: lane holds (j = j0+4q+r, i = i0+l15)
      f32x4 s = __builtin_amdgcn_mfma_f32_16x16x32_bf16(ak, bq, zero, 0, 0, 0);

      u16x4 bb = *(const u16x4*)(brow + j0 + q * 4);
      float p0, p1, p2, p3;
      {
        float b0 = __uint_as_float((unsigned)bb[0] << 16);
        float b1 = __uint_as_float((unsigned)bb[1] << 16);
        float b2 = __uint_as_float((unsigned)bb[2] << 16);
        float b3 = __uint_as_float((unsigned)bb[3] << 16);
        p0 = __builtin_amdgcn_exp2f(fmaf(s[0], CS, b0));
        p1 = __builtin_amdgcn_exp2f(fmaf(s[1], CS, b1));
        p2 = __builtin_amdgcn_exp2f(fmaf(s[2], CS, b2));
        p3 = __builtin_amdgcn_exp2f(fmaf(s[3], CS, b3));
      }
      if (jt == 21) {  // mask j = 336+4q+r >= 343
        if (4 * q + 0 >= 7) p0 = 0.f;
        if (4 * q + 1 >= 7) p1 = 0.f;
        if (4 * q + 2 >= 7) p2 = 0.f;
        if (4 * q + 3 >= 7) p3 = 0.f;
      }
      den += (p0 + p1) + (p2 + p3);

      // P already in A-frag layout for 16x16x16: A[m=i0+l15][k=4q+u]
      bf16x4 pf = pack_bf16x4(p0, p1, p2, p3);
      bf16x4 vf0 = *(const bf16x4*)(Vt + l15 * VST + j0 + q * 4);
      bf16x4 vf1 = *(const bf16x4*)(Vt + (16 + l15) * VST + j0 + q * 4);
      o0 = __builtin_amdgcn_mfma_f32_16x16x16bf16_1k(pf, vf0, o0, 0, 0, 0);
      o1 = __builtin_amdgcn_mfma_f32_16x16x16bf16_1k(pf, vf1, o1, 0, 0, 0);
    }

    // row denominators: per-lane partial (row i0+l15) -> combine quads
    den += __shfl_xor(den, 16);
    den += __shfl_xor(den, 32);

    // O D-layout: lane holds rows i = i0+4q+r, col d = l15 (+16)
    #pragma unroll
    for (int r = 0; r < 4; r++) {
      int i = i0 + 4 * q + r;
      float dr = __shfl(den, 4 * q + r);  // lane (4q+r) holds full sum for row i0+4q+r
      if (i < NTOK) {
        float inv = __builtin_amdgcn_rcpf(dr);
        size_t orow = ((size_t)b * NTOK + i) * DIMC + h * 32;
        attnout[orow + l15]      = bf16rne(o0[r] * inv);
        attnout[orow + 16 + l15] = bf16rne(o1[r] * inv);
      }
    }
  }
}

// ---------------- launch ----------------

extern "C" void kernel_launch(void* const* d_in, const int* in_sizes, int n_in,
                              void* d_out, int out_size, void* d_ws, size_t ws_size,
                              hipStream_t stream) {
  const float* x          = (const float*)d_in[0];
  const float* qkv_w      = (const float*)d_in[1];
  const float* qkv_b      = (const float*)d_in[2];
  const float* proj_w     = (const float*)d_in[3];
  const float* proj_b     = (const float*)d_in[4];
  const float* bias_table = (const float*)d_in[5];
  const int*   rel_idx    = (const int*)d_in[6];

  char* p = (char*)d_ws;
  unsigned short* xb      = (unsigned short*)p; p += (size_t)M_TOT * DIMC * 2;      // 67.4 MB
  unsigned short* wqkvT   = (unsigned short*)p; p += (size_t)QKVN * DIMC * 2;       // 0.9 MB
  unsigned short* wprojT  = (unsigned short*)p; p += (size_t)DIMC * DIMC * 2;       // 0.3 MB
  unsigned short* biasb   = (unsigned short*)p; p += (size_t)NHEAD * NTOK * NPAD * 2; // 2.9 MB
  unsigned short* qkvb    = (unsigned short*)p; p += (size_t)M_TOT * QKVN * 2;      // 202.3 MB
  unsigned short* attnout = (unsigned short*)p; p += (size_t)M_TOT * DIMC * 2;      // 67.4 MB

  cvt_x_kernel<<<(M_TOT * DIMC / 8 + 255) / 256, 256, 0, stream>>>(x, xb, M_TOT * DIMC / 8);
  prep_w_kernel<<<(QKVN * DIMC + 255) / 256, 256, 0, stream>>>(qkv_w, proj_w, wqkvT, wprojT);
  prep_bias_kernel<<<(NTOK * NPAD + 255) / 256, 256, 0, stream>>>(bias_table, rel_idx, biasb);
  gemm_bt_kernel<true><<<dim3(QKVN / 128, M_TOT / 128), 256, 0, stream>>>(
      xb, wqkvT, qkv_b, (void*)qkvb, M_TOT, QKVN, DIMC);
  attn_kernel<<<BWIN * NHEAD, 256, 0, stream>>>(qkvb, biasb, attnout);
  gemm_bt_kernel<false><<<dim3(DIMC / 128, M_TOT / 128), 256, 0, stream>>>(
      attnout, wprojT, proj_b, d_out, M_TOT, DIMC, DIMC);
}

// Round 3
// 619.205 us; speedup vs baseline: 1.1437x; 1.1437x over previous
//
#include <hip/hip_runtime.h>

// WindowAttention3D: x(256,343,384) -> qkv -> per-(b,h) softmax attention (+rel bias) -> proj
// bf16 MFMA, fp32 accum. QKV GEMM writes head-major q/k/v[h][b*343+i][32] so attention
// reads are contiguous; K staged fragment-packed in LDS via global_load_lds; S^T = K*Q^T
// so P exits QK in the A-fragment layout of mfma_16x16x16 for PV (no transpose).

#define M_TOT 87808   // 256*343
#define NTOK  343
#define NPAD  352
#define DIMC  384
#define NHEAD 12
#define QKVN  1152
#define BWIN  256
#define BSLAB (NTOK * NPAD)   // bias slab per head (f32)

typedef __bf16 bf16x8 __attribute__((ext_vector_type(8)));
typedef __bf16 bf16x4 __attribute__((ext_vector_type(4)));
typedef float f32x4 __attribute__((ext_vector_type(4)));

__device__ __forceinline__ unsigned short bf16rne(float f) {
  unsigned int u = __float_as_uint(f);
  u += 0x7fffu + ((u >> 16) & 1u);
  return (unsigned short)(u >> 16);
}

__device__ __forceinline__ unsigned int packbf(float lo, float hi) {
  return (unsigned int)bf16rne(lo) | ((unsigned int)bf16rne(hi) << 16);
}

// round-half-up bf16 pack of 4 floats -> fragment for 16x16x16 bf16 MFMA
__device__ __forceinline__ bf16x4 pack_bf16x4(float a, float b, float c, float d) {
  unsigned ua = __float_as_uint(a) + 0x8000u;
  unsigned ub = __float_as_uint(b) + 0x8000u;
  unsigned uc = __float_as_uint(c) + 0x8000u;
  unsigned ud = __float_as_uint(d) + 0x8000u;
  unsigned lo = __builtin_amdgcn_perm(ub, ua, 0x07060302u);
  unsigned hi = __builtin_amdgcn_perm(ud, uc, 0x07060302u);
  union { unsigned u[2]; bf16x4 v; } x;
  x.u[0] = lo; x.u[1] = hi;
  return x.v;
}

// ---------------- prep kernels ----------------

__global__ void cvt_x_kernel(const float* __restrict__ x, unsigned short* __restrict__ xb, int n8) {
  int i = blockIdx.x * 256 + threadIdx.x;
  if (i >= n8) return;
  const float4* xv = (const float4*)x + (size_t)i * 2;
  float4 a = xv[0], b = xv[1];
  uint4 o;
  o.x = packbf(a.x, a.y); o.y = packbf(a.z, a.w);
  o.z = packbf(b.x, b.y); o.w = packbf(b.z, b.w);
  ((uint4*)xb)[i] = o;
}

__global__ void prep_w_kernel(const float* __restrict__ qkv_w, const float* __restrict__ proj_w,
                              unsigned short* __restrict__ wqkvT, unsigned short* __restrict__ wprojT) {
  int tid = blockIdx.x * 256 + threadIdx.x;
  if (tid < QKVN * DIMC) {
    int n = tid / DIMC, k = tid - n * DIMC;
    wqkvT[tid] = bf16rne(qkv_w[(size_t)k * QKVN + n]);
  }
  if (tid < DIMC * DIMC) {
    int n = tid / DIMC, k = tid - n * DIMC;
    wprojT[tid] = bf16rne(proj_w[(size_t)k * DIMC + n]);
  }
}

// biasmat[h][i][j] = bias_table[rel_idx[i][j]][h] * log2(e); pad j>=343 -> -1e30 (exp2 -> 0)
__global__ void prep_bias_kernel(const float* __restrict__ bias_table, const int* __restrict__ rel_idx,
                                 float* __restrict__ biasmat) {
  int tid = blockIdx.x * 256 + threadIdx.x;
  if (tid >= NTOK * NPAD) return;
  int i = tid / NPAD, j = tid - i * NPAD;
  const float LOG2E = 1.44269504088896340f;
  if (j < NTOK) {
    int idx = rel_idx[i * NTOK + j];
    #pragma unroll
    for (int h = 0; h < NHEAD; h++)
      biasmat[(size_t)h * BSLAB + tid] = bias_table[idx * NHEAD + h] * LOG2E;
  } else {
    #pragma unroll
    for (int h = 0; h < NHEAD; h++)
      biasmat[(size_t)h * BSLAB + tid] = -1e30f;
  }
}

// ---------------- GEMM (A[M][K] bf16, Bt[N][K] bf16, +bias) ----------------
// OUT_MODE 0: f32 row-major [M][Nn].  OUT_MODE 1: bf16 head-major q/k/v[h][m][32].

typedef const __attribute__((address_space(1))) unsigned int* gas_t;
typedef __attribute__((address_space(3))) unsigned int* las_t;

__device__ __forceinline__ void load16_lds(const void* g, void* l) {
  __builtin_amdgcn_global_load_lds((gas_t)g, (las_t)l, 16, 0, 0);
}

template<int OUT_MODE>
__global__ __launch_bounds__(256, 3) void gemm_bt_kernel(
    const unsigned short* __restrict__ A, const unsigned short* __restrict__ Bt,
    const float* __restrict__ bias, void* __restrict__ outp,
    int M, int Nn, int K)
{
  __shared__ __attribute__((aligned(16))) unsigned short Atile[128 * 64];
  __shared__ __attribute__((aligned(16))) unsigned short Btile[128 * 64];
  const int t = threadIdx.x;
  const int lane = t & 63, w = t >> 6;
  const int q = lane >> 4, l15 = lane & 15;
  const int m0 = blockIdx.y * 128, n0 = blockIdx.x * 128;
  const int wm = w >> 1, wn = w & 1;

  f32x4 acc[4][4] = {};

  for (int kk = 0; kk < K; kk += 64) {
    #pragma unroll
    for (int i = 0; i < 4; i++) {
      int chunk = i * 256 + t;
      int r = chunk >> 3, cl = chunk & 7;
      int cg = cl ^ (r & 7);
      load16_lds(A + (size_t)(m0 + r) * K + kk + cg * 8, Atile + chunk * 8);
      load16_lds(Bt + (size_t)(n0 + r) * K + kk + cg * 8, Btile + chunk * 8);
    }
    __syncthreads();
    const bf16x8* As = (const bf16x8*)Atile;
    const bf16x8* Bs = (const bf16x8*)Btile;
    #pragma unroll
    for (int kq = 0; kq < 2; kq++) {
      bf16x8 af[4], bfr[4];
      #pragma unroll
      for (int mt = 0; mt < 4; mt++) {
        int m = wm * 64 + mt * 16 + l15;
        af[mt] = As[m * 8 + ((kq * 4 + q) ^ (m & 7))];
      }
      #pragma unroll
      for (int nt = 0; nt < 4; nt++) {
        int nr = wn * 64 + nt * 16 + l15;
        bfr[nt] = Bs[nr * 8 + ((kq * 4 + q) ^ (nr & 7))];
      }
      #pragma unroll
      for (int mt = 0; mt < 4; mt++)
        #pragma unroll
        for (int nt = 0; nt < 4; nt++)
          acc[mt][nt] = __builtin_amdgcn_mfma_f32_16x16x32_bf16(af[mt], bfr[nt], acc[mt][nt], 0, 0, 0);
    }
    __syncthreads();
  }

  #pragma unroll
  for (int nt = 0; nt < 4; nt++) {
    int nn = n0 + wn * 64 + nt * 16;      // multiple of 16
    float bv = bias[nn + l15];
    #pragma unroll
    for (int mt = 0; mt < 4; mt++) {
      int mb = m0 + wm * 64 + mt * 16 + q * 4;
      #pragma unroll
      for (int r = 0; r < 4; r++) {
        float v = acc[mt][nt][r] + bv;
        if (OUT_MODE == 0) {
          ((float*)outp)[(size_t)(mb + r) * Nn + nn + l15] = v;
        } else {
          int which = nn / DIMC;
          int hh = (nn - which * DIMC) >> 5;
          int d0 = nn & 16;
          size_t off = ((size_t)(which * NHEAD + hh) * M_TOT + (mb + r)) * 32 + d0 + l15;
          ((unsigned short*)outp)[off] = bf16rne(v);
        }
      }
    }
  }
}

// ---------------- attention: one block per (b,h); grid h-major ----------------

#define VST 360  // V^T LDS row stride (elements)

__global__ __launch_bounds__(256, 3) void attn_kernel(
    const unsigned short* __restrict__ qhead,  // [3][12][M_TOT][32] bf16
    const float* __restrict__ biasmat,         // [12][343][352] f32 (pre * log2e, pad -1e30)
    unsigned short* __restrict__ attnout)      // [M_TOT][384] bf16
{
  __shared__ __attribute__((aligned(16))) unsigned short Klds[22 * 512]; // fragment-packed
  __shared__ __attribute__((aligned(16))) unsigned short Vt[32 * VST];   // V^T[d][j]
  const int bx = blockIdx.x;
  const int h = bx >> 8, b = bx & 255;
  const int t = threadIdx.x;
  const int lane = t & 63, w = t >> 6;
  const int q = lane >> 4, l15 = lane & 15;

  const unsigned short* Qslab = qhead + ((size_t)(0 * NHEAD + h) * M_TOT + (size_t)b * NTOK) * 32;
  const unsigned short* Kslab = qhead + ((size_t)(1 * NHEAD + h) * M_TOT + (size_t)b * NTOK) * 32;
  const unsigned short* Vslab = qhead + ((size_t)(2 * NHEAD + h) * M_TOT + (size_t)b * NTOK) * 32;

  // stage K fragment-packed: Klds[jt*512 + lane*8] = K[jt*16 + l15][q*8..]
  // (dest = wave-uniform base + lane*16B; source lanes cover a contiguous 1KB -> coalesced)
  for (int jt = w; jt < 22; jt += 4)
    load16_lds(Kslab + (size_t)(jt * 16 + l15) * 32 + q * 8, Klds + jt * 512 + lane * 8);
  // jt=21 rows 343..351 read past the slab into adjacent ws data: finite bf16, masked by bias pad.

  // stage V^T with conflict-free writes (64 consecutive j per wave instr)
  for (int j = t; j < NTOK; j += 256) {
    #pragma unroll
    for (int c = 0; c < 4; c++) {
      uint4 vd = *(const uint4*)(Vslab + (size_t)j * 32 + c * 8);
      const unsigned short* vs = (const unsigned short*)&vd;
      #pragma unroll
      for (int u = 0; u < 8; u++)
        Vt[(c * 8 + u) * VST + j] = vs[u];
    }
  }
  // zero V^T pad columns j in [343,359) so p=0 * garbage can't make NaN
  for (int idx = t; idx < 32 * 16; idx += 256)
    Vt[(idx >> 4) * VST + NTOK + (idx & 15)] = 0;
  __syncthreads();

  const float* bh_bias = biasmat + (size_t)h * BSLAB;
  const float CS = 0.17677669529663689f * 1.44269504088896340f;  // scale * log2e

  // each wave: 32 query rows (two 16-row blocks) per iteration; 11 pairs total
  for (int pr = w; pr < 11; pr += 4) {
    int i0 = pr * 32;
    int iqA = i0 + l15;      iqA = iqA > (NTOK - 1) ? (NTOK - 1) : iqA;
    int iqB = i0 + 16 + l15; iqB = iqB > (NTOK - 1) ? (NTOK - 1) : iqB;
    bf16x8 bqA = *(const bf16x8*)(Qslab + (size_t)iqA * 32 + q * 8);
    bf16x8 bqB = *(const bf16x8*)(Qslab + (size_t)iqB * 32 + q * 8);
    const float* browA = bh_bias + (size_t)iqA * NPAD + 4 * q;
    const float* browB = bh_bias + (size_t)iqB * NPAD + 4 * q;

    f32x4 oA0 = {0.f,0.f,0.f,0.f}, oA1 = {0.f,0.f,0.f,0.f};
    f32x4 oB0 = {0.f,0.f,0.f,0.f}, oB1 = {0.f,0.f,0.f,0.f};
    float denA = 0.f, denB = 0.f;

    #pragma unroll 2
    for (int jt = 0; jt < 22; jt++) {
      bf16x8 ak = *(const bf16x8*)(Klds + jt * 512 + lane * 8);  // ds_read_b128, stride-1
      f32x4 z = {0.f,0.f,0.f,0.f};
      f32x4 sA = __builtin_amdgcn_mfma_f32_16x16x32_bf16(ak, bqA, z, 0, 0, 0);
      f32x4 sB = __builtin_amdgcn_mfma_f32_16x16x32_bf16(ak, bqB, z, 0, 0, 0);
      f32x4 bA = *(const f32x4*)(browA + jt * 16);
      f32x4 bB = *(const f32x4*)(browB + jt * 16);
      float pA0 = __builtin_amdgcn_exp2f(fmaf(sA[0], CS, bA[0]));
      float pA1 = __builtin_amdgcn_exp2f(fmaf(sA[1], CS, bA[1]));
      float pA2 = __builtin_amdgcn_exp2f(fmaf(sA[2], CS, bA[2]));
      float pA3 = __builtin_amdgcn_exp2f(fmaf(sA[3], CS, bA[3]));
      float pB0 = __builtin_amdgcn_exp2f(fmaf(sB[0], CS, bB[0]));
      float pB1 = __builtin_amdgcn_exp2f(fmaf(sB[1], CS, bB[1]));
      float pB2 = __builtin_amdgcn_exp2f(fmaf(sB[2], CS, bB[2]));
      float pB3 = __builtin_amdgcn_exp2f(fmaf(sB[3], CS, bB[3]));
      denA += (pA0 + pA1) + (pA2 + pA3);
      denB += (pB0 + pB1) + (pB2 + pB3);
      bf16x4 pfA = pack_bf16x4(pA0, pA1, pA2, pA3);
      bf16x4 pfB = pack_bf16x4(pB0, pB1, pB2, pB3);
      bf16x4 vf0 = *(const bf16x4*)(Vt + l15 * VST + jt * 16 + 4 * q);
      bf16x4 vf1 = *(const bf16x4*)(Vt + (16 + l15) * VST + jt * 16 + 4 * q);
      oA0 = __builtin_amdgcn_mfma_f32_16x16x16bf16_1k(pfA, vf0, oA0, 0, 0, 0);
      oA1 = __builtin_amdgcn_mfma_f32_16x16x16bf16_1k(pfA, vf1, oA1, 0, 0, 0);
      oB0 = __builtin_amdgcn_mfma_f32_16x16x16bf16_1k(pfB, vf0, oB0, 0, 0, 0);
      oB1 = __builtin_amdgcn_mfma_f32_16x16x16bf16_1k(pfB, vf1, oB1, 0, 0, 0);
    }

    denA += __shfl_xor(denA, 16); denA += __shfl_xor(denA, 32);
    denB += __shfl_xor(denB, 16); denB += __shfl_xor(denB, 32);

    #pragma unroll
    for (int r = 0; r < 4; r++) {
      int rr = 4 * q + r;
      float dA = __shfl(denA, rr);
      float dB = __shfl(denB, rr);
      int iA = i0 + rr, iB = i0 + 16 + rr;
      if (iA < NTOK) {
        float inv = __builtin_amdgcn_rcpf(dA);
        size_t orow = ((size_t)b * NTOK + iA) * DIMC + h * 32;
        attnout[orow + l15]      = bf16rne(oA0[r] * inv);
        attnout[orow + 16 + l15] = bf16rne(oA1[r] * inv);
      }
      if (iB < NTOK) {
        float inv = __builtin_amdgcn_rcpf(dB);
        size_t orow = ((size_t)b * NTOK + iB) * DIMC + h * 32;
        attnout[orow + l15]      = bf16rne(oB0[r] * inv);
        attnout[orow + 16 + l15] = bf16rne(oB1[r] * inv);
      }
    }
  }
}

// ---------------- launch ----------------

extern "C" void kernel_launch(void* const* d_in, const int* in_sizes, int n_in,
                              void* d_out, int out_size, void* d_ws, size_t ws_size,
                              hipStream_t stream) {
  const float* x          = (const float*)d_in[0];
  const float* qkv_w      = (const float*)d_in[1];
  const float* qkv_b      = (const float*)d_in[2];
  const float* proj_w     = (const float*)d_in[3];
  const float* proj_b     = (const float*)d_in[4];
  const float* bias_table = (const float*)d_in[5];
  const int*   rel_idx    = (const int*)d_in[6];

  char* p = (char*)d_ws;
  unsigned short* xb      = (unsigned short*)p; p += (size_t)M_TOT * DIMC * 2;      // 67.4 MB
  unsigned short* wqkvT   = (unsigned short*)p; p += (size_t)QKVN * DIMC * 2;       // 0.9 MB
  unsigned short* wprojT  = (unsigned short*)p; p += (size_t)DIMC * DIMC * 2;       // 0.3 MB
  float*          biasmat = (float*)p;          p += (size_t)NHEAD * BSLAB * 4;     // 5.8 MB
  unsigned short* qhead   = (unsigned short*)p; p += (size_t)3 * NHEAD * M_TOT * 32 * 2; // 202.3 MB
  unsigned short* attnout = (unsigned short*)p; p += (size_t)M_TOT * DIMC * 2;      // 67.4 MB

  cvt_x_kernel<<<(M_TOT * DIMC / 8 + 255) / 256, 256, 0, stream>>>(x, xb, M_TOT * DIMC / 8);
  prep_w_kernel<<<(QKVN * DIMC + 255) / 256, 256, 0, stream>>>(qkv_w, proj_w, wqkvT, wprojT);
  prep_bias_kernel<<<(NTOK * NPAD + 255) / 256, 256, 0, stream>>>(bias_table, rel_idx, biasmat);
  gemm_bt_kernel<1><<<dim3(QKVN / 128, M_TOT / 128), 256, 0, stream>>>(
      xb, wqkvT, qkv_b, (void*)qhead, M_TOT, QKVN, DIMC);
  attn_kernel<<<BWIN * NHEAD, 256, 0, stream>>>(qhead, biasmat, attnout);
  gemm_bt_kernel<0><<<dim3(DIMC / 128, M_TOT / 128), 256, 0, stream>>>(
      attnout, wprojT, proj_b, d_out, M_TOT, DIMC, DIMC);
}